// Round 5
// baseline (1597.801 us; speedup 1.0000x reference)
//
#include <hip/hip_runtime.h>
#include <math.h>

#define Tt 128
#define NT 1024
#define EPSF 1e-8f

typedef _Float16 f16x2 __attribute__((ext_vector_type(2)));

__device__ __forceinline__ float fsigmoid(float v) { return 1.f / (1.f + expf(-v)); }
__device__ __forceinline__ float fsoftplus(float v) { return (v > 20.f) ? v : log1pf(expf(v)); }

__device__ __forceinline__ float dot2(f16x2 a, f16x2 b, float c) {
#if __has_builtin(__builtin_amdgcn_fdot2)
  return __builtin_amdgcn_fdot2(a, b, c, false);
#else
  return c + (float)a.x * (float)b.x + (float)a.y * (float)b.y;
#endif
}

__global__ __launch_bounds__(NT, 4) void ntm_kernel(
    const float* __restrict__ x, const float* __restrict__ mem0,
    const float* __restrict__ wr0, const float* __restrict__ ww0,
    const float* __restrict__ h0, const float* __restrict__ Wx,
    const float* __restrict__ Wrd, const float* __restrict__ bh,
    const float* __restrict__ Wk, const float* __restrict__ bk,
    const float* __restrict__ Wb, const float* __restrict__ bb,
    const float* __restrict__ Wg, const float* __restrict__ bg,
    const float* __restrict__ Ws, const float* __restrict__ bs,
    const float* __restrict__ Wgam, const float* __restrict__ bgam,
    const float* __restrict__ We, const float* __restrict__ be,
    const float* __restrict__ Wa, const float* __restrict__ ba,
    float* __restrict__ out)
{
  const int b = blockIdx.x;
  const int t = threadIdx.x;
  const int lane = t & 63;
  const int wave = t >> 6;
  const int cg = t & 63;    // matmul column lane (64 cols/group)
  const int js = t >> 6;    // inner-dim slice (16 slices of 16)
  const int c4 = t & 31;    // float4 column group for mem passes
  const int rs = t >> 5;    // row slice for mem passes (32 slices)

  __shared__ __align__(16) float mem[128 * 128];   // 64 KB
  __shared__ __align__(16) float part[8192];       // 32 KB
  __shared__ __align__(16) float h_l[256];
  __shared__ __align__(16) f16x2 h16[128];         // h packed f16x2
  __shared__ __align__(16) f16x2 xr16[128];        // [x|r] packed f16x2
  __shared__ __align__(16) float er[128];
  __shared__ __align__(16) float ad[128];
  __shared__ __align__(16) float kbuf[256];
  __shared__ float wsm_l[3072];                    // 12 small-dot weight rows
  __shared__ float wr[128], ww[128];
  __shared__ float normsq[128];
  __shared__ float dotv[256];
  __shared__ float scal[12];
  __shared__ float red2[4];
  __shared__ float bias_big[512];                  // [be | ba | bk0 | bk1]
  __shared__ float bh_l[256];
  __shared__ float bias_sm[12];

  // ===== persistent f16-packed register weights (96 regs/thread) =====
  // big4: 512 cols = [We | Wa | Wk0 | Wk1], inner 256. Thread: 16 j x 8 cols.
  f16x2 wbig[64];
  {
    #pragma unroll
    for (int c = 0; c < 8; ++c) {
      const int mat = c >> 1;
      const float* base = (mat == 0) ? We : (mat == 1) ? Wa : (mat == 2) ? Wk : (Wk + 256 * 128);
      const float* bp = base + (c & 1) * 64 + cg;
      #pragma unroll
      for (int jj = 0; jj < 8; ++jj) {
        const int row = js * 16 + 2 * jj;
        f16x2 w;
        w.x = (_Float16)bp[row * 128];
        w.y = (_Float16)bp[(row + 1) * 128];
        wbig[c * 8 + jj] = w;
      }
    }
  }
  // C-matmul: 256 cols = [Wx;Wrd], inner 256 = [x|r]. Thread: 16 j x 4 cols.
  f16x2 wcreg[32];
  {
    const float* basep = (js < 8) ? (Wx + (js * 16) * 256) : (Wrd + ((js - 8) * 16) * 256);
    #pragma unroll
    for (int c = 0; c < 4; ++c) {
      const float* bp = basep + c * 64 + cg;
      #pragma unroll
      for (int jj = 0; jj < 8; ++jj) {
        f16x2 w;
        w.x = (_Float16)bp[(2 * jj) * 256];
        w.y = (_Float16)bp[(2 * jj + 1) * 256];
        wcreg[c * 8 + jj] = w;
      }
    }
  }

  // ===== state / bias / small-weight init =====
  for (int i = t; i < 128 * 128; i += NT) mem[i] = mem0[i];
  if (t < 128) { wr[t] = wr0[b * 128 + t]; ww[t] = ww0[b * 128 + t]; }
  if (t < 256) {
    float v = h0[b * 256 + t];
    h_l[t] = v; bh_l[t] = bh[t];
    float vo = __shfl_xor(v, 1);
    if (!(t & 1)) { f16x2 p; p.x = (_Float16)v; p.y = (_Float16)vo; h16[t >> 1] = p; }
  }
  if (t < 512) bias_big[t] = (t < 128) ? be[t] : (t < 256) ? ba[t - 128] : bk[t - 256];
  for (int i = t; i < 3072; i += NT) {
    const int d = i >> 8, j = i & 255;
    const int head = d / 6, kind = d % 6;
    float v;
    if (kind == 0)      v = Wb[head * 256 + j];
    else if (kind == 1) v = Wg[head * 256 + j];
    else if (kind == 2) v = Wgam[head * 256 + j];
    else                v = Ws[head * 768 + j * 3 + (kind - 3)];
    wsm_l[i] = v;
  }
  if (t < 12) {
    const int head = t / 6, kind = t % 6;
    bias_sm[t] = (kind == 0) ? bb[head] : (kind == 1) ? bg[head]
               : (kind == 2) ? bgam[head] : bs[head * 3 + (kind - 3)];
  }
  __syncthreads();

  // ---- big4 matmul partials from h16 (8 cols x 8 f16x2 per thread)
  auto phase_big4 = [&]() {
    float acc[8];
    #pragma unroll
    for (int c = 0; c < 8; ++c) acc[c] = 0.f;
    #pragma unroll
    for (int jj = 0; jj < 8; ++jj) {
      const f16x2 hh = h16[js * 8 + jj];   // wave-uniform -> LDS broadcast
      #pragma unroll
      for (int c = 0; c < 8; ++c) acc[c] = dot2(hh, wbig[c * 8 + jj], acc[c]);
    }
    #pragma unroll
    for (int c = 0; c < 8; ++c) part[js * 512 + c * 64 + cg] = acc[c];
  };

  // ---- reduce big4 -> er/ad/kbuf + k^2 + 12 small dots from h_l
  auto phase_reduce = [&]() {
    if (t < 512) {
      float v = bias_big[t];
      #pragma unroll
      for (int s = 0; s < 16; ++s) v += part[s * 512 + t];
      float ks = 0.f;
      if (t < 128)      er[t] = fsigmoid(v);
      else if (t < 256) ad[t - 128] = tanhf(v);
      else { float kv = tanhf(v); kbuf[t - 256] = kv; ks = kv * kv; }
      #pragma unroll
      for (int m = 32; m >= 1; m >>= 1) ks += __shfl_xor(ks, m);
      if (wave >= 4 && lane == 0) red2[wave - 4] = ks;
    }
    if (t < 384) {
      const int d = t >> 5, l5 = t & 31;
      float s = 0.f;
      #pragma unroll
      for (int q = 0; q < 8; ++q) s += h_l[l5 + 32 * q] * wsm_l[d * 256 + l5 + 32 * q];
      #pragma unroll
      for (int m = 16; m >= 1; m >>= 1) s += __shfl_xor(s, m);
      if (l5 == 0) scal[d] = s + bias_sm[d];
    }
  };

  // prologue: er/ad for step 0 from h0
  phase_big4();
  __syncthreads();
  phase_reduce();
  __syncthreads();

  for (int step = 0; step < Tt; ++step) {
    // ---- P1: x_t load+pack (64 lanes, float2); mem erase/add; normsq; r partials
    if (t < 64) {
      const float2 xv = reinterpret_cast<const float2*>(x + ((size_t)b * Tt + step) * 128)[t];
      f16x2 p; p.x = (_Float16)xv.x; p.y = (_Float16)xv.y;
      xr16[t] = p;
    }
    {
      const float4 e4 = *reinterpret_cast<const float4*>(&er[c4 * 4]);
      const float4 a4 = *reinterpret_cast<const float4*>(&ad[c4 * 4]);
      float rx = 0.f, ry = 0.f, rz = 0.f, rw = 0.f;
      #pragma unroll
      for (int k = 0; k < 4; ++k) {
        const int n = rs + 32 * k;
        const float wwn = ww[n], wrn = wr[n];
        float4 v = *reinterpret_cast<const float4*>(&mem[n * 128 + c4 * 4]);
        v.x = v.x * (1.f - wwn * e4.x) + wwn * a4.x;
        v.y = v.y * (1.f - wwn * e4.y) + wwn * a4.y;
        v.z = v.z * (1.f - wwn * e4.z) + wwn * a4.z;
        v.w = v.w * (1.f - wwn * e4.w) + wwn * a4.w;
        *reinterpret_cast<float4*>(&mem[n * 128 + c4 * 4]) = v;
        float nsq = v.x * v.x + v.y * v.y + v.z * v.z + v.w * v.w;
        #pragma unroll
        for (int m = 16; m >= 1; m >>= 1) nsq += __shfl_xor(nsq, m);
        if (c4 == 0) normsq[n] = nsq;
        rx += wrn * v.x; ry += wrn * v.y; rz += wrn * v.z; rw += wrn * v.w;
      }
      *reinterpret_cast<float4*>(&part[rs * 128 + c4 * 4]) = make_float4(rx, ry, rz, rw);
    }
    __syncthreads();  // b1

    // ---- P2: reduce r; pack into xr16[64..]
    if (t < 128) {
      float r = 0.f;
      #pragma unroll
      for (int s = 0; s < 32; ++s) r += part[s * 128 + t];
      float ro = __shfl_xor(r, 1);
      if (!(t & 1)) { f16x2 p; p.x = (_Float16)r; p.y = (_Float16)ro; xr16[64 + (t >> 1)] = p; }
    }
    __syncthreads();  // b2

    // ---- P3: C-matmul partials (4 cols x 8 f16x2 per thread)
    {
      float acc[4];
      #pragma unroll
      for (int c = 0; c < 4; ++c) acc[c] = 0.f;
      #pragma unroll
      for (int jj = 0; jj < 8; ++jj) {
        const f16x2 xx = xr16[js * 8 + jj];
        #pragma unroll
        for (int c = 0; c < 4; ++c) acc[c] = dot2(xx, wcreg[c * 8 + jj], acc[c]);
      }
      #pragma unroll
      for (int c = 0; c < 4; ++c) part[js * 256 + c * 64 + cg] = acc[c];
    }
    __syncthreads();  // b3

    // ---- P4: h = tanh(.); write out; pack h16
    if (t < 256) {
      float v = bh_l[t];
      #pragma unroll
      for (int s = 0; s < 16; ++s) v += part[s * 256 + t];
      v = tanhf(v);
      h_l[t] = v;
      out[((size_t)b * Tt + step) * 256 + t] = v;
      float vo = __shfl_xor(v, 1);
      if (!(t & 1)) { f16x2 p; p.x = (_Float16)v; p.y = (_Float16)vo; h16[t >> 1] = p; }
    }
    __syncthreads();  // b4

    // ---- P5/P6: big4 + reduce (er',ad',k,scal,k^2) from new h
    phase_big4();
    __syncthreads();  // b5
    phase_reduce();
    __syncthreads();  // b6

    // ---- P7: content dots, both heads (8 rows/thread)
    {
      const int head = t >> 9;
      const int u = t & 511;
      const int cc = u & 31, ns = u >> 5;
      const float4 k4 = *reinterpret_cast<const float4*>(&kbuf[head * 128 + cc * 4]);
      float d0[8];
      #pragma unroll
      for (int ii = 0; ii < 8; ++ii) {
        const int n = ns * 8 + ii;
        const float4 m4 = *reinterpret_cast<const float4*>(&mem[n * 128 + cc * 4]);
        d0[ii] = k4.x * m4.x + k4.y * m4.y + k4.z * m4.z + k4.w * m4.w;
      }
      #pragma unroll
      for (int m = 16; m >= 1; m >>= 1) {
        #pragma unroll
        for (int ii = 0; ii < 8; ++ii) d0[ii] += __shfl_xor(d0[ii], m);
      }
      if (cc == 0) {
        #pragma unroll
        for (int ii = 0; ii < 8; ++ii) dotv[head * 128 + ns * 8 + ii] = d0[ii];
      }
    }
    __syncthreads();  // b7

    // ---- P8: addressing tail, wave0=head0, wave1=head1
    if (wave < 2) {
      const int head = wave;
      const int h6 = head * 6;
      const float beta  = fsoftplus(scal[h6]);
      const float g     = fsigmoid(scal[h6 + 1]);
      const float gamma = 1.f + fsoftplus(scal[h6 + 2]);
      float e0 = scal[h6 + 3], e1 = scal[h6 + 4], e2 = scal[h6 + 5];
      const float mx3 = fmaxf(e0, fmaxf(e1, e2));
      float x0 = expf(e0 - mx3), x1 = expf(e1 - mx3), x2 = expf(e2 - mx3);
      const float si = 1.f / (x0 + x1 + x2);
      const float s0 = x0 * si, s1 = x1 * si, s2 = x2 * si;
      const float knorm = sqrtf(red2[2 * head] + red2[2 * head + 1]);
      float* wprev = head ? ww : wr;
      const int n0 = 2 * lane, n1 = 2 * lane + 1;
      float l0 = beta * dotv[head * 128 + n0] / (knorm * sqrtf(normsq[n0]) + EPSF);
      float l1 = beta * dotv[head * 128 + n1] / (knorm * sqrtf(normsq[n1]) + EPSF);
      float mx = fmaxf(l0, l1);
      #pragma unroll
      for (int m = 32; m >= 1; m >>= 1) mx = fmaxf(mx, __shfl_xor(mx, m));
      float q0 = expf(l0 - mx), q1 = expf(l1 - mx);
      float sm = q0 + q1;
      #pragma unroll
      for (int m = 32; m >= 1; m >>= 1) sm += __shfl_xor(sm, m);
      const float inv = 1.f / sm;
      const float wg0 = g * q0 * inv + (1.f - g) * wprev[n0];
      const float wg1 = g * q1 * inv + (1.f - g) * wprev[n1];
      const float wgl = __shfl(wg1, (lane + 63) & 63);
      const float wgr = __shfl(wg0, (lane + 1) & 63);
      const float sh0 = s0 * wgl + s1 * wg0 + s2 * wg1;
      const float sh1 = s0 * wg0 + s1 * wg1 + s2 * wgr;
      const float wp0 = exp2f(gamma * log2f(sh0));
      const float wp1 = exp2f(gamma * log2f(sh1));
      float tot = wp0 + wp1;
      #pragma unroll
      for (int m = 32; m >= 1; m >>= 1) tot += __shfl_xor(tot, m);
      const float itot = 1.f / (tot + EPSF);
      wprev[n0] = wp0 * itot;
      wprev[n1] = wp1 * itot;
    }
    __syncthreads();  // b8
  }
}

extern "C" void kernel_launch(void* const* d_in, const int* in_sizes, int n_in,
                              void* d_out, int out_size, void* d_ws, size_t ws_size,
                              hipStream_t stream) {
  const float* x    = (const float*)d_in[0];
  const float* mem0 = (const float*)d_in[1];
  const float* wr0  = (const float*)d_in[2];
  const float* ww0  = (const float*)d_in[3];
  const float* h0   = (const float*)d_in[4];
  const float* Wx   = (const float*)d_in[5];
  const float* Wrd  = (const float*)d_in[6];
  const float* bh   = (const float*)d_in[7];
  const float* Wk   = (const float*)d_in[8];
  const float* bk   = (const float*)d_in[9];
  const float* Wb   = (const float*)d_in[10];
  const float* bb   = (const float*)d_in[11];
  const float* Wg   = (const float*)d_in[12];
  const float* bg   = (const float*)d_in[13];
  const float* Ws   = (const float*)d_in[14];
  const float* bs   = (const float*)d_in[15];
  const float* Wgam = (const float*)d_in[16];
  const float* bgam = (const float*)d_in[17];
  const float* We   = (const float*)d_in[18];
  const float* be   = (const float*)d_in[19];
  const float* Wa   = (const float*)d_in[20];
  const float* ba   = (const float*)d_in[21];
  float* out = (float*)d_out;

  hipLaunchKernelGGL(ntm_kernel, dim3(128), dim3(NT), 0, stream,
                     x, mem0, wr0, ww0, h0, Wx, Wrd, bh, Wk, bk, Wb, bb,
                     Wg, bg, Ws, bs, Wgam, bgam, We, be, Wa, ba, out);
}

// Round 6
// 1556.092 us; speedup vs baseline: 1.0268x; 1.0268x over previous
//
#include <hip/hip_runtime.h>
#include <math.h>

#define Tt 128
#define NT 1024
#define EPSF 1e-8f

typedef _Float16 f16x2 __attribute__((ext_vector_type(2)));

__device__ __forceinline__ float fsigmoid(float v) { return 1.f / (1.f + expf(-v)); }
__device__ __forceinline__ float fsoftplus(float v) { return (v > 20.f) ? v : log1pf(expf(v)); }
__device__ __forceinline__ float ftanh(float v) { float e = expf(2.f * v); return 1.f - 2.f / (e + 1.f); }

__device__ __forceinline__ float dot2(f16x2 a, f16x2 b, float c) {
#if __has_builtin(__builtin_amdgcn_fdot2)
  return __builtin_amdgcn_fdot2(a, b, c, false);
#else
  return c + (float)a.x * (float)b.x + (float)a.y * (float)b.y;
#endif
}
__device__ __forceinline__ f16x2 pack2(float a, float b) {
  f16x2 p; p.x = (_Float16)a; p.y = (_Float16)b; return p;
}

// ---- DPP reduction primitives (VALU-speed, no LDS pipe) ----
template <int C> __device__ __forceinline__ float dppadd(float v) {
  int s = __builtin_amdgcn_update_dpp(0, __builtin_bit_cast(int, v), C, 0xf, 0xf, true);
  return v + __builtin_bit_cast(float, s);
}
template <int C> __device__ __forceinline__ float dppmax(float v) {
  int iv = __builtin_bit_cast(int, v);
  int s = __builtin_amdgcn_update_dpp(iv, iv, C, 0xf, 0xf, false);
  return fmaxf(v, __builtin_bit_cast(float, s));
}
// after halfsum: lane31 = sum(lanes 0..31), lane63 = sum(lanes 32..63)
__device__ __forceinline__ float halfsum(float v) {
  v = dppadd<0x111>(v); v = dppadd<0x112>(v); v = dppadd<0x114>(v);
  v = dppadd<0x118>(v); v = dppadd<0x142>(v);
  return v;
}
__device__ __forceinline__ float allsum(float v) {
  v = halfsum(v); v = dppadd<0x143>(v);
  return __builtin_bit_cast(float, __builtin_amdgcn_readlane(__builtin_bit_cast(int, v), 63));
}
__device__ __forceinline__ float allmax(float v) {
  v = dppmax<0x111>(v); v = dppmax<0x112>(v); v = dppmax<0x114>(v);
  v = dppmax<0x118>(v); v = dppmax<0x142>(v); v = dppmax<0x143>(v);
  return __builtin_bit_cast(float, __builtin_amdgcn_readlane(__builtin_bit_cast(int, v), 63));
}

__global__ __launch_bounds__(NT, 4) void ntm_kernel(
    const float* __restrict__ x, const float* __restrict__ mem0,
    const float* __restrict__ wr0, const float* __restrict__ ww0,
    const float* __restrict__ h0, const float* __restrict__ Wx,
    const float* __restrict__ Wrd, const float* __restrict__ bh,
    const float* __restrict__ Wk, const float* __restrict__ bk,
    const float* __restrict__ Wb, const float* __restrict__ bb,
    const float* __restrict__ Wg, const float* __restrict__ bg,
    const float* __restrict__ Ws, const float* __restrict__ bs,
    const float* __restrict__ Wgam, const float* __restrict__ bgam,
    const float* __restrict__ We, const float* __restrict__ be,
    const float* __restrict__ Wa, const float* __restrict__ ba,
    float* __restrict__ out)
{
  const int b = blockIdx.x;
  const int t = threadIdx.x;
  const int lane = t & 63;
  const int wave = t >> 6;
  const int cg = t & 63;    // matmul column lane
  const int js = t >> 6;    // inner-dim slice (16 slices of 16)
  const int c4 = t & 31;    // float4 column group for mem passes
  const int rs = t >> 5;    // row slice for mem passes (32 slices)

  __shared__ __align__(16) float mem[128 * 128];   // 64 KB
  __shared__ __align__(16) float part[8192];       // 32 KB
  __shared__ __align__(16) float h_l[256];
  __shared__ __align__(16) float xf[128];          // x_t (f32)
  __shared__ __align__(16) float rf[128];          // r   (f32)
  __shared__ __align__(16) float er[128];
  __shared__ __align__(16) float ad[128];
  __shared__ __align__(16) float kbuf[256];
  __shared__ float wsm_l[3072];
  __shared__ float wr[128], ww[128];
  __shared__ float normsq[128];
  __shared__ float dotv[256];
  __shared__ float scal[12];
  __shared__ float red2[4];
  __shared__ float bias_big[512];                  // [be | ba | bk0 | bk1]
  __shared__ float bh_l[256];
  __shared__ float bias_sm[12];

  // ===== persistent f16-packed register weights (96 regs/thread) =====
  f16x2 wbig[64];
  {
    #pragma unroll
    for (int c = 0; c < 8; ++c) {
      const int mat = c >> 1;
      const float* base = (mat == 0) ? We : (mat == 1) ? Wa : (mat == 2) ? Wk : (Wk + 256 * 128);
      const float* bp = base + (c & 1) * 64 + cg;
      #pragma unroll
      for (int jj = 0; jj < 8; ++jj) {
        const int row = js * 16 + 2 * jj;
        wbig[c * 8 + jj] = pack2(bp[row * 128], bp[(row + 1) * 128]);
      }
    }
  }
  f16x2 wcreg[32];
  {
    const float* basep = (js < 8) ? (Wx + (js * 16) * 256) : (Wrd + ((js - 8) * 16) * 256);
    #pragma unroll
    for (int c = 0; c < 4; ++c) {
      const float* bp = basep + c * 64 + cg;
      #pragma unroll
      for (int jj = 0; jj < 8; ++jj) {
        wcreg[c * 8 + jj] = pack2(bp[(2 * jj) * 256], bp[(2 * jj + 1) * 256]);
      }
    }
  }

  // ===== state / bias / small-weight init =====
  for (int i = t; i < 128 * 128; i += NT) mem[i] = mem0[i];
  if (t < 128) { wr[t] = wr0[b * 128 + t]; ww[t] = ww0[b * 128 + t]; }
  if (t < 256) { h_l[t] = h0[b * 256 + t]; bh_l[t] = bh[t]; }
  if (t < 512) bias_big[t] = (t < 128) ? be[t] : (t < 256) ? ba[t - 128] : bk[t - 256];
  for (int i = t; i < 3072; i += NT) {
    const int d = i >> 8, j = i & 255;
    const int head = d / 6, kind = d % 6;
    float v;
    if (kind == 0)      v = Wb[head * 256 + j];
    else if (kind == 1) v = Wg[head * 256 + j];
    else if (kind == 2) v = Wgam[head * 256 + j];
    else                v = Ws[head * 768 + j * 3 + (kind - 3)];
    wsm_l[i] = v;
  }
  if (t < 12) {
    const int head = t / 6, kind = t % 6;
    bias_sm[t] = (kind == 0) ? bb[head] : (kind == 1) ? bg[head]
               : (kind == 2) ? bgam[head] : bs[head * 3 + (kind - 3)];
  }
  __syncthreads();

  // ---- big4 matmul partials from h_l (cvt at consumer)
  auto phase_big4 = [&]() {
    float acc[8];
    #pragma unroll
    for (int c = 0; c < 8; ++c) acc[c] = 0.f;
    #pragma unroll
    for (int jj = 0; jj < 8; ++jj) {
      const float2 h2 = *reinterpret_cast<const float2*>(&h_l[js * 16 + 2 * jj]);
      const f16x2 hh = pack2(h2.x, h2.y);
      #pragma unroll
      for (int c = 0; c < 8; ++c) acc[c] = dot2(hh, wbig[c * 8 + jj], acc[c]);
    }
    #pragma unroll
    for (int c = 0; c < 8; ++c) part[js * 512 + c * 64 + cg] = acc[c];
  };

  // ---- reduce big4 -> er/ad/kbuf + k^2 (DPP) + 12 small dots (DPP)
  auto phase_reduce = [&]() {
    if (t < 512) {
      float v = bias_big[t];
      #pragma unroll
      for (int s = 0; s < 16; ++s) v += part[s * 512 + t];
      if (t < 128)      er[t] = fsigmoid(v);
      else if (t < 256) ad[t - 128] = ftanh(v);
      else {
        float kv = ftanh(v);
        kbuf[t - 256] = kv;
        float ks = kv * kv;
        ks = halfsum(ks); ks = dppadd<0x143>(ks);
        if (lane == 63) red2[wave - 4] = ks;
      }
    }
    if (t < 384) {
      const int d = t >> 5, l5 = t & 31;
      float s = 0.f;
      #pragma unroll
      for (int q = 0; q < 8; ++q) s += h_l[l5 + 32 * q] * wsm_l[d * 256 + l5 + 32 * q];
      s = halfsum(s);
      if ((lane & 31) == 31) scal[d] = s + bias_sm[d];
    }
  };

  // prologue: er/ad/k/scal for step 0 from h0
  phase_big4();
  __syncthreads();
  phase_reduce();
  __syncthreads();

  for (int step = 0; step < Tt; ++step) {
    // ---- P1: x_t -> xf; mem erase/add update; r partials (no reductions here)
    if (t < 128) xf[t] = x[((size_t)b * Tt + step) * 128 + t];
    {
      const float4 e4 = *reinterpret_cast<const float4*>(&er[c4 * 4]);
      const float4 a4 = *reinterpret_cast<const float4*>(&ad[c4 * 4]);
      float rx = 0.f, ry = 0.f, rz = 0.f, rw = 0.f;
      #pragma unroll
      for (int k = 0; k < 4; ++k) {
        const int n = rs + 32 * k;
        const float wwn = ww[n], wrn = wr[n];
        float4 v = *reinterpret_cast<const float4*>(&mem[n * 128 + c4 * 4]);
        v.x = v.x * (1.f - wwn * e4.x) + wwn * a4.x;
        v.y = v.y * (1.f - wwn * e4.y) + wwn * a4.y;
        v.z = v.z * (1.f - wwn * e4.z) + wwn * a4.z;
        v.w = v.w * (1.f - wwn * e4.w) + wwn * a4.w;
        *reinterpret_cast<float4*>(&mem[n * 128 + c4 * 4]) = v;
        rx += wrn * v.x; ry += wrn * v.y; rz += wrn * v.z; rw += wrn * v.w;
      }
      *reinterpret_cast<float4*>(&part[rs * 128 + c4 * 4]) = make_float4(rx, ry, rz, rw);
    }
    __syncthreads();  // b1

    // ---- P2: reduce r partials (f32, no pack)
    if (t < 128) {
      float r = 0.f;
      #pragma unroll
      for (int s = 0; s < 32; ++s) r += part[s * 128 + t];
      rf[t] = r;
    }
    __syncthreads();  // b2

    // ---- P3: C-matmul partials from [xf|rf] (cvt at consumer)
    {
      const float* src = (js < 8) ? (xf + js * 16) : (rf + (js - 8) * 16);
      float acc[4];
      #pragma unroll
      for (int c = 0; c < 4; ++c) acc[c] = 0.f;
      #pragma unroll
      for (int jj = 0; jj < 8; ++jj) {
        const float2 s2 = *reinterpret_cast<const float2*>(&src[2 * jj]);
        const f16x2 xx = pack2(s2.x, s2.y);
        #pragma unroll
        for (int c = 0; c < 4; ++c) acc[c] = dot2(xx, wcreg[c * 8 + jj], acc[c]);
      }
      #pragma unroll
      for (int c = 0; c < 4; ++c) part[js * 256 + c * 64 + cg] = acc[c];
    }
    __syncthreads();  // b3

    // ---- P4: h = tanh(.); write out
    if (t < 256) {
      float v = bh_l[t];
      #pragma unroll
      for (int s = 0; s < 16; ++s) v += part[s * 256 + t];
      v = ftanh(v);
      h_l[t] = v;
      out[((size_t)b * Tt + step) * 256 + t] = v;
    }
    __syncthreads();  // b4

    // ---- P5/P6: big4 + reduce from new h
    phase_big4();
    __syncthreads();  // b5
    phase_reduce();
    __syncthreads();  // b6

    // ---- P7: content dots + row normsq fused (DPP half-reduction)
    {
      const int head = t >> 9;
      const int u = t & 511;
      const int cc = u & 31, ns = u >> 5;
      const float4 k4 = *reinterpret_cast<const float4*>(&kbuf[head * 128 + cc * 4]);
      float dsum[8], qsum[8];
      #pragma unroll
      for (int ii = 0; ii < 8; ++ii) {
        const int n = ns * 8 + ii;
        const float4 m4 = *reinterpret_cast<const float4*>(&mem[n * 128 + cc * 4]);
        dsum[ii] = k4.x * m4.x + k4.y * m4.y + k4.z * m4.z + k4.w * m4.w;
        qsum[ii] = m4.x * m4.x + m4.y * m4.y + m4.z * m4.z + m4.w * m4.w;
      }
      #pragma unroll
      for (int ii = 0; ii < 8; ++ii) dsum[ii] = halfsum(dsum[ii]);
      if (head == 0) {
        #pragma unroll
        for (int ii = 0; ii < 8; ++ii) qsum[ii] = halfsum(qsum[ii]);
      }
      if ((lane & 31) == 31) {
        #pragma unroll
        for (int ii = 0; ii < 8; ++ii) dotv[head * 128 + ns * 8 + ii] = dsum[ii];
        if (head == 0) {
          #pragma unroll
          for (int ii = 0; ii < 8; ++ii) normsq[ns * 8 + ii] = qsum[ii];
        }
      }
    }
    __syncthreads();  // b7

    // ---- P8: addressing tail, wave0=head0, wave1=head1 (DPP all-reduces)
    if (wave < 2) {
      const int head = wave;
      const int h6 = head * 6;
      const float beta  = fsoftplus(scal[h6]);
      const float g     = fsigmoid(scal[h6 + 1]);
      const float gamma = 1.f + fsoftplus(scal[h6 + 2]);
      float e0 = scal[h6 + 3], e1 = scal[h6 + 4], e2 = scal[h6 + 5];
      const float mx3 = fmaxf(e0, fmaxf(e1, e2));
      float x0 = expf(e0 - mx3), x1 = expf(e1 - mx3), x2 = expf(e2 - mx3);
      const float si = 1.f / (x0 + x1 + x2);
      const float s0 = x0 * si, s1 = x1 * si, s2 = x2 * si;
      const float knorm = sqrtf(red2[2 * head] + red2[2 * head + 1]);
      float* wprev = head ? ww : wr;
      const int n0 = 2 * lane, n1 = 2 * lane + 1;
      float l0 = beta * dotv[head * 128 + n0] / (knorm * sqrtf(normsq[n0]) + EPSF);
      float l1 = beta * dotv[head * 128 + n1] / (knorm * sqrtf(normsq[n1]) + EPSF);
      const float mx = allmax(fmaxf(l0, l1));
      float q0 = expf(l0 - mx), q1 = expf(l1 - mx);
      const float inv = 1.f / allsum(q0 + q1);
      const float wg0 = g * q0 * inv + (1.f - g) * wprev[n0];
      const float wg1 = g * q1 * inv + (1.f - g) * wprev[n1];
      const float wgl = __shfl(wg1, (lane + 63) & 63);
      const float wgr = __shfl(wg0, (lane + 1) & 63);
      const float sh0 = s0 * wgl + s1 * wg0 + s2 * wg1;
      const float sh1 = s0 * wg0 + s1 * wg1 + s2 * wgr;
      const float wp0 = exp2f(gamma * log2f(sh0));
      const float wp1 = exp2f(gamma * log2f(sh1));
      const float itot = 1.f / (allsum(wp0 + wp1) + EPSF);
      wprev[n0] = wp0 * itot;
      wprev[n1] = wp1 * itot;
    }
    __syncthreads();  // b8
  }
}

extern "C" void kernel_launch(void* const* d_in, const int* in_sizes, int n_in,
                              void* d_out, int out_size, void* d_ws, size_t ws_size,
                              hipStream_t stream) {
  const float* x    = (const float*)d_in[0];
  const float* mem0 = (const float*)d_in[1];
  const float* wr0  = (const float*)d_in[2];
  const float* ww0  = (const float*)d_in[3];
  const float* h0   = (const float*)d_in[4];
  const float* Wx   = (const float*)d_in[5];
  const float* Wrd  = (const float*)d_in[6];
  const float* bh   = (const float*)d_in[7];
  const float* Wk   = (const float*)d_in[8];
  const float* bk   = (const float*)d_in[9];
  const float* Wb   = (const float*)d_in[10];
  const float* bb   = (const float*)d_in[11];
  const float* Wg   = (const float*)d_in[12];
  const float* bg   = (const float*)d_in[13];
  const float* Ws   = (const float*)d_in[14];
  const float* bs   = (const float*)d_in[15];
  const float* Wgam = (const float*)d_in[16];
  const float* bgam = (const float*)d_in[17];
  const float* We   = (const float*)d_in[18];
  const float* be   = (const float*)d_in[19];
  const float* Wa   = (const float*)d_in[20];
  const float* ba   = (const float*)d_in[21];
  float* out = (float*)d_out;

  hipLaunchKernelGGL(ntm_kernel, dim3(128), dim3(NT), 0, stream,
                     x, mem0, wr0, ww0, h0, Wx, Wrd, bh, Wk, bk, Wb, bb,
                     Wg, bg, Ws, bs, Wgam, bgam, We, be, Wa, ba, out);
}

// Round 7
// 1186.367 us; speedup vs baseline: 1.3468x; 1.3116x over previous
//
#include <hip/hip_runtime.h>
#include <math.h>

#define Tt 128
#define NT 512
#define EPSF 1e-8f

typedef _Float16 f16x2 __attribute__((ext_vector_type(2)));

__device__ __forceinline__ float fsigmoid(float v) { return 1.f / (1.f + expf(-v)); }
__device__ __forceinline__ float fsoftplus(float v) { return (v > 20.f) ? v : log1pf(expf(v)); }
__device__ __forceinline__ float ftanh(float v) { float e = expf(2.f * v); return 1.f - 2.f / (e + 1.f); }

__device__ __forceinline__ float dot2(f16x2 a, f16x2 b, float c) {
#if __has_builtin(__builtin_amdgcn_fdot2)
  return __builtin_amdgcn_fdot2(a, b, c, false);
#else
  return c + (float)a.x * (float)b.x + (float)a.y * (float)b.y;
#endif
}
__device__ __forceinline__ f16x2 pack2(float a, float b) {
  f16x2 p; p.x = (_Float16)a; p.y = (_Float16)b; return p;
}

// ---- DPP reduction primitives ----
template <int C> __device__ __forceinline__ float dppadd(float v) {
  int s = __builtin_amdgcn_update_dpp(0, __builtin_bit_cast(int, v), C, 0xf, 0xf, true);
  return v + __builtin_bit_cast(float, s);
}
template <int C> __device__ __forceinline__ float dppmax(float v) {
  int iv = __builtin_bit_cast(int, v);
  int s = __builtin_amdgcn_update_dpp(iv, iv, C, 0xf, 0xf, false);
  return fmaxf(v, __builtin_bit_cast(float, s));
}
// after halfsum: lane31 = sum(lanes 0..31), lane63 = sum(lanes 32..63)
__device__ __forceinline__ float halfsum(float v) {
  v = dppadd<0x111>(v); v = dppadd<0x112>(v); v = dppadd<0x114>(v);
  v = dppadd<0x118>(v); v = dppadd<0x142>(v);
  return v;
}
__device__ __forceinline__ float allsum(float v) {
  v = halfsum(v); v = dppadd<0x143>(v);
  return __builtin_bit_cast(float, __builtin_amdgcn_readlane(__builtin_bit_cast(int, v), 63));
}
__device__ __forceinline__ float allmax(float v) {
  v = dppmax<0x111>(v); v = dppmax<0x112>(v); v = dppmax<0x114>(v);
  v = dppmax<0x118>(v); v = dppmax<0x142>(v); v = dppmax<0x143>(v);
  return __builtin_bit_cast(float, __builtin_amdgcn_readlane(__builtin_bit_cast(int, v), 63));
}

__global__ __launch_bounds__(NT, 1) void ntm_kernel(
    const float* __restrict__ x, const float* __restrict__ mem0,
    const float* __restrict__ wr0, const float* __restrict__ ww0,
    const float* __restrict__ h0, const float* __restrict__ Wx,
    const float* __restrict__ Wrd, const float* __restrict__ bh,
    const float* __restrict__ Wk, const float* __restrict__ bk,
    const float* __restrict__ Wb, const float* __restrict__ bb,
    const float* __restrict__ Wg, const float* __restrict__ bg,
    const float* __restrict__ Ws, const float* __restrict__ bs,
    const float* __restrict__ Wgam, const float* __restrict__ bgam,
    const float* __restrict__ We, const float* __restrict__ be,
    const float* __restrict__ Wa, const float* __restrict__ ba,
    float* __restrict__ out)
{
  const int b = blockIdx.x;
  const int t = threadIdx.x;
  const int lane = t & 63;
  const int wave = t >> 6;
  const int cg = t & 63;    // matmul column lane
  const int js = t >> 6;    // inner-dim slice (8 slices of 32)
  const int c4 = t & 31;    // float4 column group for mem passes
  const int rs = t >> 5;    // row slice for mem passes (16 slices)

  __shared__ __align__(16) float mem[128 * 128];   // 64 KB
  __shared__ __align__(16) float part[4096];       // 16 KB
  __shared__ __align__(16) float h_l[256];
  __shared__ __align__(16) float xf[128];
  __shared__ __align__(16) float rf[128];
  __shared__ __align__(16) float er[128];
  __shared__ __align__(16) float ad[128];
  __shared__ __align__(16) float kbuf[256];
  __shared__ float wsm_l[3072];
  __shared__ float wr[128], ww[128];
  __shared__ float normsq[128];
  __shared__ float dotv[256];
  __shared__ float scal[12];
  __shared__ float red2[4];
  __shared__ float bias_big[512];                  // [be | ba | bk0 | bk1]
  __shared__ float bh_l[256];
  __shared__ float bias_sm[12];

  // ===== persistent f16-packed register weights (192 regs/thread @ 512 thr) =====
  // big4: 512 cols = [We | Wa | Wk0 | Wk1], inner 256. Thread: 32 j x 8 cols.
  f16x2 wbig[128];
  {
    #pragma unroll
    for (int c = 0; c < 8; ++c) {
      const int mat = c >> 1;
      const float* base = (mat == 0) ? We : (mat == 1) ? Wa : (mat == 2) ? Wk : (Wk + 256 * 128);
      const float* bp = base + (c & 1) * 64 + cg;
      #pragma unroll
      for (int jj = 0; jj < 16; ++jj) {
        const int row = js * 32 + 2 * jj;
        wbig[c * 16 + jj] = pack2(bp[row * 128], bp[(row + 1) * 128]);
      }
    }
  }
  // C-matmul: 256 cols = [Wx;Wrd], inner 256 = [x|r]. Thread: 32 j x 4 cols.
  f16x2 wcreg[64];
  {
    const float* basep = (js < 4) ? (Wx + (js * 32) * 256) : (Wrd + ((js - 4) * 32) * 256);
    #pragma unroll
    for (int c = 0; c < 4; ++c) {
      const float* bp = basep + c * 64 + cg;
      #pragma unroll
      for (int jj = 0; jj < 16; ++jj) {
        wcreg[c * 16 + jj] = pack2(bp[(2 * jj) * 256], bp[(2 * jj + 1) * 256]);
      }
    }
  }

  // ===== state / bias / small-weight init =====
  for (int i = t; i < 128 * 128; i += NT) mem[i] = mem0[i];
  if (t < 128) { wr[t] = wr0[b * 128 + t]; ww[t] = ww0[b * 128 + t]; }
  if (t < 256) { h_l[t] = h0[b * 256 + t]; bh_l[t] = bh[t]; }
  bias_big[t] = (t < 128) ? be[t] : (t < 256) ? ba[t - 128] : bk[t - 256];
  for (int i = t; i < 3072; i += NT) {
    const int d = i >> 8, j = i & 255;
    const int head = d / 6, kind = d % 6;
    float v;
    if (kind == 0)      v = Wb[head * 256 + j];
    else if (kind == 1) v = Wg[head * 256 + j];
    else if (kind == 2) v = Wgam[head * 256 + j];
    else                v = Ws[head * 768 + j * 3 + (kind - 3)];
    wsm_l[i] = v;
  }
  if (t < 12) {
    const int head = t / 6, kind = t % 6;
    bias_sm[t] = (kind == 0) ? bb[head] : (kind == 1) ? bg[head]
               : (kind == 2) ? bgam[head] : bs[head * 3 + (kind - 3)];
  }
  __syncthreads();

  // ---- big4 matmul partials from h_l (cvt at consumer)
  auto phase_big4 = [&]() {
    float acc[8];
    #pragma unroll
    for (int c = 0; c < 8; ++c) acc[c] = 0.f;
    #pragma unroll
    for (int jj = 0; jj < 16; ++jj) {
      const float2 h2 = *reinterpret_cast<const float2*>(&h_l[js * 32 + 2 * jj]);
      const f16x2 hh = pack2(h2.x, h2.y);
      #pragma unroll
      for (int c = 0; c < 8; ++c) acc[c] = dot2(hh, wbig[c * 16 + jj], acc[c]);
    }
    #pragma unroll
    for (int c = 0; c < 8; ++c) part[js * 512 + c * 64 + cg] = acc[c];
  };

  // ---- reduce big4 -> er/ad/kbuf + k^2 (DPP) + 12 small dots (DPP)
  auto phase_reduce = [&]() {
    {
      float v = bias_big[t];
      #pragma unroll
      for (int s = 0; s < 8; ++s) v += part[s * 512 + t];
      if (t < 128)      er[t] = fsigmoid(v);
      else if (t < 256) ad[t - 128] = ftanh(v);
      else {
        float kv = ftanh(v);
        kbuf[t - 256] = kv;
        float ks = kv * kv;
        ks = halfsum(ks); ks = dppadd<0x143>(ks);
        if (lane == 63) red2[wave - 4] = ks;
      }
    }
    if (t < 384) {
      const int d = t >> 5, l5 = t & 31;
      float s = 0.f;
      #pragma unroll
      for (int q = 0; q < 8; ++q) s += h_l[l5 + 32 * q] * wsm_l[d * 256 + l5 + 32 * q];
      s = halfsum(s);
      if ((lane & 31) == 31) scal[d] = s + bias_sm[d];
    }
  };

  // prologue: er/ad/k/scal for step 0 from h0
  phase_big4();
  __syncthreads();
  phase_reduce();
  __syncthreads();

  for (int step = 0; step < Tt; ++step) {
    // ---- P1: x_t -> xf; mem erase/add update; r partials
    if (t < 128) xf[t] = x[((size_t)b * Tt + step) * 128 + t];
    {
      const float4 e4 = *reinterpret_cast<const float4*>(&er[c4 * 4]);
      const float4 a4 = *reinterpret_cast<const float4*>(&ad[c4 * 4]);
      float rx = 0.f, ry = 0.f, rz = 0.f, rw = 0.f;
      #pragma unroll
      for (int k = 0; k < 8; ++k) {
        const int n = rs + 16 * k;
        const float wwn = ww[n], wrn = wr[n];
        float4 v = *reinterpret_cast<const float4*>(&mem[n * 128 + c4 * 4]);
        v.x = v.x * (1.f - wwn * e4.x) + wwn * a4.x;
        v.y = v.y * (1.f - wwn * e4.y) + wwn * a4.y;
        v.z = v.z * (1.f - wwn * e4.z) + wwn * a4.z;
        v.w = v.w * (1.f - wwn * e4.w) + wwn * a4.w;
        *reinterpret_cast<float4*>(&mem[n * 128 + c4 * 4]) = v;
        rx += wrn * v.x; ry += wrn * v.y; rz += wrn * v.z; rw += wrn * v.w;
      }
      *reinterpret_cast<float4*>(&part[rs * 128 + c4 * 4]) = make_float4(rx, ry, rz, rw);
    }
    __syncthreads();  // b1

    // ---- P2: reduce r partials
    if (t < 128) {
      float r = 0.f;
      #pragma unroll
      for (int s = 0; s < 16; ++s) r += part[s * 128 + t];
      rf[t] = r;
    }
    __syncthreads();  // b2

    // ---- P3: C-matmul partials from [xf|rf] (cvt at consumer)
    {
      const float* src = (js < 4) ? (xf + js * 32) : (rf + (js - 4) * 32);
      float acc[4];
      #pragma unroll
      for (int c = 0; c < 4; ++c) acc[c] = 0.f;
      #pragma unroll
      for (int jj = 0; jj < 16; ++jj) {
        const float2 s2 = *reinterpret_cast<const float2*>(&src[2 * jj]);
        const f16x2 xx = pack2(s2.x, s2.y);
        #pragma unroll
        for (int c = 0; c < 4; ++c) acc[c] = dot2(xx, wcreg[c * 16 + jj], acc[c]);
      }
      #pragma unroll
      for (int c = 0; c < 4; ++c) part[js * 256 + c * 64 + cg] = acc[c];
    }
    __syncthreads();  // b3

    // ---- P4: h = tanh(.); write out
    if (t < 256) {
      float v = bh_l[t];
      #pragma unroll
      for (int s = 0; s < 8; ++s) v += part[s * 256 + t];
      v = ftanh(v);
      h_l[t] = v;
      out[((size_t)b * Tt + step) * 256 + t] = v;
    }
    __syncthreads();  // b4

    // ---- P5/P6: big4 + reduce from new h
    phase_big4();
    __syncthreads();  // b5
    phase_reduce();
    __syncthreads();  // b6

    // ---- P7: content dots + row normsq fused (DPP half-reduction)
    {
      const int head = t >> 8;           // waves 0-3: head0, 4-7: head1
      const int u = t & 255;
      const int cc = u & 31, ns = u >> 5; // half-wave owns 16 rows
      const float4 k4 = *reinterpret_cast<const float4*>(&kbuf[head * 128 + cc * 4]);
      #pragma unroll
      for (int ch = 0; ch < 2; ++ch) {
        float dsum[8], qsum[8];
        #pragma unroll
        for (int ii = 0; ii < 8; ++ii) {
          const int n = ns * 16 + ch * 8 + ii;
          const float4 m4 = *reinterpret_cast<const float4*>(&mem[n * 128 + cc * 4]);
          dsum[ii] = k4.x * m4.x + k4.y * m4.y + k4.z * m4.z + k4.w * m4.w;
          qsum[ii] = m4.x * m4.x + m4.y * m4.y + m4.z * m4.z + m4.w * m4.w;
        }
        #pragma unroll
        for (int ii = 0; ii < 8; ++ii) dsum[ii] = halfsum(dsum[ii]);
        if (head == 0) {
          #pragma unroll
          for (int ii = 0; ii < 8; ++ii) qsum[ii] = halfsum(qsum[ii]);
        }
        if ((lane & 31) == 31) {
          #pragma unroll
          for (int ii = 0; ii < 8; ++ii) dotv[head * 128 + ns * 16 + ch * 8 + ii] = dsum[ii];
          if (head == 0) {
            #pragma unroll
            for (int ii = 0; ii < 8; ++ii) normsq[ns * 16 + ch * 8 + ii] = qsum[ii];
          }
        }
      }
    }
    __syncthreads();  // b7

    // ---- P8: addressing tail, wave0=head0, wave1=head1 (DPP all-reduces)
    if (wave < 2) {
      const int head = wave;
      const int h6 = head * 6;
      const float beta  = fsoftplus(scal[h6]);
      const float g     = fsigmoid(scal[h6 + 1]);
      const float gamma = 1.f + fsoftplus(scal[h6 + 2]);
      float e0 = scal[h6 + 3], e1 = scal[h6 + 4], e2 = scal[h6 + 5];
      const float mx3 = fmaxf(e0, fmaxf(e1, e2));
      float x0 = expf(e0 - mx3), x1 = expf(e1 - mx3), x2 = expf(e2 - mx3);
      const float si = 1.f / (x0 + x1 + x2);
      const float s0 = x0 * si, s1 = x1 * si, s2 = x2 * si;
      const float knorm = sqrtf(red2[2 * head] + red2[2 * head + 1]);
      float* wprev = head ? ww : wr;
      const int n0 = 2 * lane, n1 = 2 * lane + 1;
      float l0 = beta * dotv[head * 128 + n0] / (knorm * sqrtf(normsq[n0]) + EPSF);
      float l1 = beta * dotv[head * 128 + n1] / (knorm * sqrtf(normsq[n1]) + EPSF);
      const float mx = allmax(fmaxf(l0, l1));
      float q0 = expf(l0 - mx), q1 = expf(l1 - mx);
      const float inv = 1.f / allsum(q0 + q1);
      const float wg0 = g * q0 * inv + (1.f - g) * wprev[n0];
      const float wg1 = g * q1 * inv + (1.f - g) * wprev[n1];
      const float wgl = __shfl(wg1, (lane + 63) & 63);
      const float wgr = __shfl(wg0, (lane + 1) & 63);
      const float sh0 = s0 * wgl + s1 * wg0 + s2 * wg1;
      const float sh1 = s0 * wg0 + s1 * wg1 + s2 * wgr;
      const float wp0 = exp2f(gamma * log2f(sh0));
      const float wp1 = exp2f(gamma * log2f(sh1));
      const float itot = 1.f / (allsum(wp0 + wp1) + EPSF);
      wprev[n0] = wp0 * itot;
      wprev[n1] = wp1 * itot;
    }
    __syncthreads();  // b8
  }
}

extern "C" void kernel_launch(void* const* d_in, const int* in_sizes, int n_in,
                              void* d_out, int out_size, void* d_ws, size_t ws_size,
                              hipStream_t stream) {
  const float* x    = (const float*)d_in[0];
  const float* mem0 = (const float*)d_in[1];
  const float* wr0  = (const float*)d_in[2];
  const float* ww0  = (const float*)d_in[3];
  const float* h0   = (const float*)d_in[4];
  const float* Wx   = (const float*)d_in[5];
  const float* Wrd  = (const float*)d_in[6];
  const float* bh   = (const float*)d_in[7];
  const float* Wk   = (const float*)d_in[8];
  const float* bk   = (const float*)d_in[9];
  const float* Wb   = (const float*)d_in[10];
  const float* bb   = (const float*)d_in[11];
  const float* Wg   = (const float*)d_in[12];
  const float* bg   = (const float*)d_in[13];
  const float* Ws   = (const float*)d_in[14];
  const float* bs   = (const float*)d_in[15];
  const float* Wgam = (const float*)d_in[16];
  const float* bgam = (const float*)d_in[17];
  const float* We   = (const float*)d_in[18];
  const float* be   = (const float*)d_in[19];
  const float* Wa   = (const float*)d_in[20];
  const float* ba   = (const float*)d_in[21];
  float* out = (float*)d_out;

  hipLaunchKernelGGL(ntm_kernel, dim3(128), dim3(NT), 0, stream,
                     x, mem0, wr0, ww0, h0, Wx, Wrd, bh, Wk, bk, Wb, bb,
                     Wg, bg, Ws, bs, Wgam, bgam, We, be, Wa, ba, out);
}

// Round 8
// 1185.585 us; speedup vs baseline: 1.3477x; 1.0007x over previous
//
#include <hip/hip_runtime.h>
#include <math.h>

#define Tt 128
#define NT 512
#define EPSF 1e-8f

typedef _Float16 f16x2 __attribute__((ext_vector_type(2)));

__device__ __forceinline__ float fsigmoid(float v) { return 1.f / (1.f + expf(-v)); }
__device__ __forceinline__ float fsoftplus(float v) { return (v > 20.f) ? v : log1pf(expf(v)); }
__device__ __forceinline__ float ftanh(float v) { float e = expf(2.f * v); return 1.f - 2.f / (e + 1.f); }

__device__ __forceinline__ float dot2(f16x2 a, f16x2 b, float c) {
#if __has_builtin(__builtin_amdgcn_fdot2)
  return __builtin_amdgcn_fdot2(a, b, c, false);
#else
  return c + (float)a.x * (float)b.x + (float)a.y * (float)b.y;
#endif
}
__device__ __forceinline__ f16x2 pack2(float a, float b) {
  f16x2 p; p.x = (_Float16)a; p.y = (_Float16)b; return p;
}

// ---- DPP reduction primitives ----
template <int C> __device__ __forceinline__ float dppadd(float v) {
  int s = __builtin_amdgcn_update_dpp(0, __builtin_bit_cast(int, v), C, 0xf, 0xf, true);
  return v + __builtin_bit_cast(float, s);
}
template <int C> __device__ __forceinline__ float dppmax(float v) {
  int iv = __builtin_bit_cast(int, v);
  int s = __builtin_amdgcn_update_dpp(iv, iv, C, 0xf, 0xf, false);
  return fmaxf(v, __builtin_bit_cast(float, s));
}
// after halfsum: lane31 = sum(lanes 0..31), lane63 = sum(lanes 32..63)
__device__ __forceinline__ float halfsum(float v) {
  v = dppadd<0x111>(v); v = dppadd<0x112>(v); v = dppadd<0x114>(v);
  v = dppadd<0x118>(v); v = dppadd<0x142>(v);
  return v;
}
__device__ __forceinline__ float allsum(float v) {
  v = halfsum(v); v = dppadd<0x143>(v);
  return __builtin_bit_cast(float, __builtin_amdgcn_readlane(__builtin_bit_cast(int, v), 63));
}
__device__ __forceinline__ float allmax(float v) {
  v = dppmax<0x111>(v); v = dppmax<0x112>(v); v = dppmax<0x114>(v);
  v = dppmax<0x118>(v); v = dppmax<0x142>(v); v = dppmax<0x143>(v);
  return __builtin_bit_cast(float, __builtin_amdgcn_readlane(__builtin_bit_cast(int, v), 63));
}

__global__
__attribute__((amdgpu_flat_work_group_size(NT, NT), amdgpu_waves_per_eu(2, 2)))
void ntm_kernel(
    const float* __restrict__ x, const float* __restrict__ mem0,
    const float* __restrict__ wr0, const float* __restrict__ ww0,
    const float* __restrict__ h0, const float* __restrict__ Wx,
    const float* __restrict__ Wrd, const float* __restrict__ bh,
    const float* __restrict__ Wk, const float* __restrict__ bk,
    const float* __restrict__ Wb, const float* __restrict__ bb,
    const float* __restrict__ Wg, const float* __restrict__ bg,
    const float* __restrict__ Ws, const float* __restrict__ bs,
    const float* __restrict__ Wgam, const float* __restrict__ bgam,
    const float* __restrict__ We, const float* __restrict__ be,
    const float* __restrict__ Wa, const float* __restrict__ ba,
    float* __restrict__ out)
{
  const int b = blockIdx.x;
  const int t = threadIdx.x;
  const int lane = t & 63;
  const int wave = t >> 6;
  const int cg = t & 63;    // matmul column lane
  const int js = t >> 6;    // inner-dim slice (8 slices of 32)
  const int c4 = t & 31;    // float4 column group for mem passes
  const int rs = t >> 5;    // row slice for mem passes (16 slices)

  __shared__ __align__(16) float mem[128 * 128];   // 64 KB
  __shared__ __align__(16) float part[4096];       // 16 KB
  __shared__ __align__(16) float h_l[256];
  __shared__ __align__(16) float xf[128];
  __shared__ __align__(16) float rf[128];
  __shared__ __align__(16) float er[128];
  __shared__ __align__(16) float ad[128];
  __shared__ __align__(16) float kbuf[256];
  __shared__ float wsm_l[3072];
  __shared__ float wr[128], ww[128];
  __shared__ float normsq[128];
  __shared__ float dotv[256];
  __shared__ float scal[12];
  __shared__ float red2[4];
  __shared__ float bias_big[512];                  // [be | ba | bk0 | bk1]
  __shared__ float bh_l[256];
  __shared__ float bias_sm[12];

  // ===== persistent f16-packed register weights (192 regs/thread @ 512 thr) =====
  // big4: 512 cols = [We | Wa | Wk0 | Wk1], inner 256. Thread: 32 j x 8 cols.
  f16x2 wbig[128];
  {
    #pragma unroll
    for (int c = 0; c < 8; ++c) {
      const int mat = c >> 1;
      const float* base = (mat == 0) ? We : (mat == 1) ? Wa : (mat == 2) ? Wk : (Wk + 256 * 128);
      const float* bp = base + (c & 1) * 64 + cg;
      #pragma unroll
      for (int jj = 0; jj < 16; ++jj) {
        const int row = js * 32 + 2 * jj;
        wbig[c * 16 + jj] = pack2(bp[row * 128], bp[(row + 1) * 128]);
      }
    }
  }
  // C-matmul: 256 cols = [Wx;Wrd], inner 256 = [x|r]. Thread: 32 j x 4 cols.
  f16x2 wcreg[64];
  {
    const float* basep = (js < 4) ? (Wx + (js * 32) * 256) : (Wrd + ((js - 4) * 32) * 256);
    #pragma unroll
    for (int c = 0; c < 4; ++c) {
      const float* bp = basep + c * 64 + cg;
      #pragma unroll
      for (int jj = 0; jj < 16; ++jj) {
        wcreg[c * 16 + jj] = pack2(bp[(2 * jj) * 256], bp[(2 * jj + 1) * 256]);
      }
    }
  }

  // ===== state / bias / small-weight init =====
  for (int i = t; i < 128 * 128; i += NT) mem[i] = mem0[i];
  if (t < 128) { wr[t] = wr0[b * 128 + t]; ww[t] = ww0[b * 128 + t]; }
  if (t < 256) { h_l[t] = h0[b * 256 + t]; bh_l[t] = bh[t]; }
  bias_big[t] = (t < 128) ? be[t] : (t < 256) ? ba[t - 128] : bk[t - 256];
  for (int i = t; i < 3072; i += NT) {
    const int d = i >> 8, j = i & 255;
    const int head = d / 6, kind = d % 6;
    float v;
    if (kind == 0)      v = Wb[head * 256 + j];
    else if (kind == 1) v = Wg[head * 256 + j];
    else if (kind == 2) v = Wgam[head * 256 + j];
    else                v = Ws[head * 768 + j * 3 + (kind - 3)];
    wsm_l[i] = v;
  }
  if (t < 12) {
    const int head = t / 6, kind = t % 6;
    bias_sm[t] = (kind == 0) ? bb[head] : (kind == 1) ? bg[head]
               : (kind == 2) ? bgam[head] : bs[head * 3 + (kind - 3)];
  }
  __syncthreads();

  // ---- big4 matmul partials from h_l (cvt at consumer)
  auto phase_big4 = [&]() {
    float acc[8];
    #pragma unroll
    for (int c = 0; c < 8; ++c) acc[c] = 0.f;
    #pragma unroll
    for (int jj = 0; jj < 16; ++jj) {
      const float2 h2 = *reinterpret_cast<const float2*>(&h_l[js * 32 + 2 * jj]);
      const f16x2 hh = pack2(h2.x, h2.y);
      #pragma unroll
      for (int c = 0; c < 8; ++c) acc[c] = dot2(hh, wbig[c * 16 + jj], acc[c]);
    }
    #pragma unroll
    for (int c = 0; c < 8; ++c) part[js * 512 + c * 64 + cg] = acc[c];
  };

  // ---- reduce big4 -> er/ad/kbuf + k^2 (DPP) + 12 small dots (DPP)
  auto phase_reduce = [&]() {
    {
      float v = bias_big[t];
      #pragma unroll
      for (int s = 0; s < 8; ++s) v += part[s * 512 + t];
      if (t < 128)      er[t] = fsigmoid(v);
      else if (t < 256) ad[t - 128] = ftanh(v);
      else {
        float kv = ftanh(v);
        kbuf[t - 256] = kv;
        float ks = kv * kv;
        ks = halfsum(ks); ks = dppadd<0x143>(ks);
        if (lane == 63) red2[wave - 4] = ks;
      }
    }
    if (t < 384) {
      const int d = t >> 5, l5 = t & 31;
      float s = 0.f;
      #pragma unroll
      for (int q = 0; q < 8; ++q) s += h_l[l5 + 32 * q] * wsm_l[d * 256 + l5 + 32 * q];
      s = halfsum(s);
      if ((lane & 31) == 31) scal[d] = s + bias_sm[d];
    }
  };

  // prologue: er/ad/k/scal for step 0 from h0
  phase_big4();
  __syncthreads();
  phase_reduce();
  __syncthreads();

  for (int step = 0; step < Tt; ++step) {
    // ---- P1: x_t -> xf; mem erase/add update; r partials
    if (t < 128) xf[t] = x[((size_t)b * Tt + step) * 128 + t];
    {
      const float4 e4 = *reinterpret_cast<const float4*>(&er[c4 * 4]);
      const float4 a4 = *reinterpret_cast<const float4*>(&ad[c4 * 4]);
      float rx = 0.f, ry = 0.f, rz = 0.f, rw = 0.f;
      #pragma unroll
      for (int k = 0; k < 8; ++k) {
        const int n = rs + 16 * k;
        const float wwn = ww[n], wrn = wr[n];
        float4 v = *reinterpret_cast<const float4*>(&mem[n * 128 + c4 * 4]);
        v.x = v.x * (1.f - wwn * e4.x) + wwn * a4.x;
        v.y = v.y * (1.f - wwn * e4.y) + wwn * a4.y;
        v.z = v.z * (1.f - wwn * e4.z) + wwn * a4.z;
        v.w = v.w * (1.f - wwn * e4.w) + wwn * a4.w;
        *reinterpret_cast<float4*>(&mem[n * 128 + c4 * 4]) = v;
        rx += wrn * v.x; ry += wrn * v.y; rz += wrn * v.z; rw += wrn * v.w;
      }
      *reinterpret_cast<float4*>(&part[rs * 128 + c4 * 4]) = make_float4(rx, ry, rz, rw);
    }
    __syncthreads();  // b1

    // ---- P2: reduce r partials
    if (t < 128) {
      float r = 0.f;
      #pragma unroll
      for (int s = 0; s < 16; ++s) r += part[s * 128 + t];
      rf[t] = r;
    }
    __syncthreads();  // b2

    // ---- P3: C-matmul partials from [xf|rf] (cvt at consumer)
    {
      const float* src = (js < 4) ? (xf + js * 32) : (rf + (js - 4) * 32);
      float acc[4];
      #pragma unroll
      for (int c = 0; c < 4; ++c) acc[c] = 0.f;
      #pragma unroll
      for (int jj = 0; jj < 16; ++jj) {
        const float2 s2 = *reinterpret_cast<const float2*>(&src[2 * jj]);
        const f16x2 xx = pack2(s2.x, s2.y);
        #pragma unroll
        for (int c = 0; c < 4; ++c) acc[c] = dot2(xx, wcreg[c * 16 + jj], acc[c]);
      }
      #pragma unroll
      for (int c = 0; c < 4; ++c) part[js * 256 + c * 64 + cg] = acc[c];
    }
    __syncthreads();  // b3

    // ---- P4: h = tanh(.); write out
    if (t < 256) {
      float v = bh_l[t];
      #pragma unroll
      for (int s = 0; s < 8; ++s) v += part[s * 256 + t];
      v = ftanh(v);
      h_l[t] = v;
      out[((size_t)b * Tt + step) * 256 + t] = v;
    }
    __syncthreads();  // b4

    // ---- P5/P6: big4 + reduce from new h
    phase_big4();
    __syncthreads();  // b5
    phase_reduce();
    __syncthreads();  // b6

    // ---- P7: content dots + row normsq fused (DPP half-reduction)
    {
      const int head = t >> 8;           // waves 0-3: head0, 4-7: head1
      const int u = t & 255;
      const int cc = u & 31, ns = u >> 5; // half-wave owns 16 rows
      const float4 k4 = *reinterpret_cast<const float4*>(&kbuf[head * 128 + cc * 4]);
      #pragma unroll
      for (int ch = 0; ch < 2; ++ch) {
        float dsum[8], qsum[8];
        #pragma unroll
        for (int ii = 0; ii < 8; ++ii) {
          const int n = ns * 16 + ch * 8 + ii;
          const float4 m4 = *reinterpret_cast<const float4*>(&mem[n * 128 + cc * 4]);
          dsum[ii] = k4.x * m4.x + k4.y * m4.y + k4.z * m4.z + k4.w * m4.w;
          qsum[ii] = m4.x * m4.x + m4.y * m4.y + m4.z * m4.z + m4.w * m4.w;
        }
        #pragma unroll
        for (int ii = 0; ii < 8; ++ii) dsum[ii] = halfsum(dsum[ii]);
        if (head == 0) {
          #pragma unroll
          for (int ii = 0; ii < 8; ++ii) qsum[ii] = halfsum(qsum[ii]);
        }
        if ((lane & 31) == 31) {
          #pragma unroll
          for (int ii = 0; ii < 8; ++ii) dotv[head * 128 + ns * 16 + ch * 8 + ii] = dsum[ii];
          if (head == 0) {
            #pragma unroll
            for (int ii = 0; ii < 8; ++ii) normsq[ns * 16 + ch * 8 + ii] = qsum[ii];
          }
        }
      }
    }
    __syncthreads();  // b7

    // ---- P8: addressing tail, wave0=head0, wave1=head1 (DPP all-reduces)
    if (wave < 2) {
      const int head = wave;
      const int h6 = head * 6;
      const float beta  = fsoftplus(scal[h6]);
      const float g     = fsigmoid(scal[h6 + 1]);
      const float gamma = 1.f + fsoftplus(scal[h6 + 2]);
      float e0 = scal[h6 + 3], e1 = scal[h6 + 4], e2 = scal[h6 + 5];
      const float mx3 = fmaxf(e0, fmaxf(e1, e2));
      float x0 = expf(e0 - mx3), x1 = expf(e1 - mx3), x2 = expf(e2 - mx3);
      const float si = 1.f / (x0 + x1 + x2);
      const float s0 = x0 * si, s1 = x1 * si, s2 = x2 * si;
      const float knorm = sqrtf(red2[2 * head] + red2[2 * head + 1]);
      float* wprev = head ? ww : wr;
      const int n0 = 2 * lane, n1 = 2 * lane + 1;
      float l0 = beta * dotv[head * 128 + n0] / (knorm * sqrtf(normsq[n0]) + EPSF);
      float l1 = beta * dotv[head * 128 + n1] / (knorm * sqrtf(normsq[n1]) + EPSF);
      const float mx = allmax(fmaxf(l0, l1));
      float q0 = expf(l0 - mx), q1 = expf(l1 - mx);
      const float inv = 1.f / allsum(q0 + q1);
      const float wg0 = g * q0 * inv + (1.f - g) * wprev[n0];
      const float wg1 = g * q1 * inv + (1.f - g) * wprev[n1];
      const float wgl = __shfl(wg1, (lane + 63) & 63);
      const float wgr = __shfl(wg0, (lane + 1) & 63);
      const float sh0 = s0 * wgl + s1 * wg0 + s2 * wg1;
      const float sh1 = s0 * wg0 + s1 * wg1 + s2 * wgr;
      const float wp0 = exp2f(gamma * log2f(sh0));
      const float wp1 = exp2f(gamma * log2f(sh1));
      const float itot = 1.f / (allsum(wp0 + wp1) + EPSF);
      wprev[n0] = wp0 * itot;
      wprev[n1] = wp1 * itot;
    }
    __syncthreads();  // b8
  }
}

extern "C" void kernel_launch(void* const* d_in, const int* in_sizes, int n_in,
                              void* d_out, int out_size, void* d_ws, size_t ws_size,
                              hipStream_t stream) {
  const float* x    = (const float*)d_in[0];
  const float* mem0 = (const float*)d_in[1];
  const float* wr0  = (const float*)d_in[2];
  const float* ww0  = (const float*)d_in[3];
  const float* h0   = (const float*)d_in[4];
  const float* Wx   = (const float*)d_in[5];
  const float* Wrd  = (const float*)d_in[6];
  const float* bh   = (const float*)d_in[7];
  const float* Wk   = (const float*)d_in[8];
  const float* bk   = (const float*)d_in[9];
  const float* Wb   = (const float*)d_in[10];
  const float* bb   = (const float*)d_in[11];
  const float* Wg   = (const float*)d_in[12];
  const float* bg   = (const float*)d_in[13];
  const float* Ws   = (const float*)d_in[14];
  const float* bs   = (const float*)d_in[15];
  const float* Wgam = (const float*)d_in[16];
  const float* bgam = (const float*)d_in[17];
  const float* We   = (const float*)d_in[18];
  const float* be   = (const float*)d_in[19];
  const float* Wa   = (const float*)d_in[20];
  const float* ba   = (const float*)d_in[21];
  float* out = (float*)d_out;

  hipLaunchKernelGGL(ntm_kernel, dim3(128), dim3(NT), 0, stream,
                     x, mem0, wr0, ww0, h0, Wx, Wrd, bh, Wk, bk, Wb, bb,
                     Wg, bg, Ws, bs, Wgam, bgam, We, be, Wa, ba, out);
}

// Round 10
// 1089.253 us; speedup vs baseline: 1.4669x; 1.0884x over previous
//
#include <hip/hip_runtime.h>
#include <math.h>

#define Tt 128
#define NT 512
#define EPSF 1e-8f

typedef _Float16 f16x2 __attribute__((ext_vector_type(2)));

__device__ __forceinline__ float fsigmoid(float v) { return 1.f / (1.f + expf(-v)); }
__device__ __forceinline__ float fsoftplus(float v) { return (v > 20.f) ? v : log1pf(expf(v)); }
__device__ __forceinline__ float ftanh(float v) { float e = expf(2.f * v); return 1.f - 2.f / (e + 1.f); }

__device__ __forceinline__ float dot2(f16x2 a, f16x2 b, float c) {
#if __has_builtin(__builtin_amdgcn_fdot2)
  return __builtin_amdgcn_fdot2(a, b, c, false);
#else
  return c + (float)a.x * (float)b.x + (float)a.y * (float)b.y;
#endif
}
__device__ __forceinline__ f16x2 pack2(float a, float b) {
  f16x2 p; p.x = (_Float16)a; p.y = (_Float16)b; return p;
}

// ---- DPP reduction primitives ----
template <int C> __device__ __forceinline__ float dppadd(float v) {
  int s = __builtin_amdgcn_update_dpp(0, __builtin_bit_cast(int, v), C, 0xf, 0xf, true);
  return v + __builtin_bit_cast(float, s);
}
template <int C> __device__ __forceinline__ float dppmax(float v) {
  int iv = __builtin_bit_cast(int, v);
  int s = __builtin_amdgcn_update_dpp(iv, iv, C, 0xf, 0xf, false);
  return fmaxf(v, __builtin_bit_cast(float, s));
}
__device__ __forceinline__ float halfsum(float v) {
  v = dppadd<0x111>(v); v = dppadd<0x112>(v); v = dppadd<0x114>(v);
  v = dppadd<0x118>(v); v = dppadd<0x142>(v);
  return v;
}
__device__ __forceinline__ float allsum(float v) {
  v = halfsum(v); v = dppadd<0x143>(v);
  return __builtin_bit_cast(float, __builtin_amdgcn_readlane(__builtin_bit_cast(int, v), 63));
}
__device__ __forceinline__ float allmax(float v) {
  v = dppmax<0x111>(v); v = dppmax<0x112>(v); v = dppmax<0x114>(v);
  v = dppmax<0x118>(v); v = dppmax<0x142>(v); v = dppmax<0x143>(v);
  return __builtin_bit_cast(float, __builtin_amdgcn_readlane(__builtin_bit_cast(int, v), 63));
}

// ===== prep: pack big4 weights [We|Wa|Wk0|Wk1] f32 -> f16x2 in streaming layout =====
// uint index i = (((c*8 + js)*4 + jj4)*64 + cg)*4 + e ; jj = jj4*4+e
// value = pack2(W[row0*128+col], W[(row0+1)*128+col]), row0 = js*32+2*jj, col=(c&1)*64+cg
__global__ __launch_bounds__(512, 1) void ntm_prep(
    const float* __restrict__ We, const float* __restrict__ Wa,
    const float* __restrict__ Wk, unsigned int* __restrict__ wsb)
{
  const int i = blockIdx.x * 512 + threadIdx.x;   // grid 128*512 = 65536
  const int e = i & 3;
  const int cg = (i >> 2) & 63;
  const int jj4 = (i >> 8) & 3;
  const int js = (i >> 10) & 7;
  const int c = (i >> 13) & 7;
  const int jj = jj4 * 4 + e;
  const int mat = c >> 1;
  const int col = (c & 1) * 64 + cg;
  const int row0 = js * 32 + 2 * jj;
  const float* base = (mat == 0) ? We : (mat == 1) ? Wa : (mat == 2) ? Wk : (Wk + 256 * 128);
  wsb[i] = __builtin_bit_cast(unsigned int, pack2(base[row0 * 128 + col], base[(row0 + 1) * 128 + col]));
}

__global__ __launch_bounds__(NT, 1) void ntm_kernel(
    const float* __restrict__ x, const float* __restrict__ mem0,
    const float* __restrict__ wr0, const float* __restrict__ ww0,
    const float* __restrict__ h0, const float* __restrict__ Wx,
    const float* __restrict__ Wrd, const float* __restrict__ bh,
    const float* __restrict__ bk,
    const float* __restrict__ Wb, const float* __restrict__ bb,
    const float* __restrict__ Wg, const float* __restrict__ bg,
    const float* __restrict__ Ws, const float* __restrict__ bs,
    const float* __restrict__ Wgam, const float* __restrict__ bgam,
    const float* __restrict__ be, const float* __restrict__ ba,
    const uint4* __restrict__ wsb,
    float* __restrict__ out)
{
  const int b = blockIdx.x;
  const int t = threadIdx.x;
  const int lane = t & 63;
  const int wave = t >> 6;
  const int cg = t & 63;    // matmul column lane
  const int js = t >> 6;    // inner-dim slice (8 slices of 32)
  const int c4 = t & 31;    // float4 column group for mem passes
  const int rs = t >> 5;    // row slice for mem passes (16 slices)

  __shared__ __align__(16) float mem[128 * 128];   // 64 KB
  __shared__ __align__(16) float part[4096];       // 16 KB
  __shared__ __align__(16) float h_l[256];
  __shared__ __align__(16) float xf[128];
  __shared__ __align__(16) float rf[128];
  __shared__ __align__(16) float er[128];
  __shared__ __align__(16) float ad[128];
  __shared__ __align__(16) float kbuf[256];
  __shared__ float wsm_l[3072];
  __shared__ float wr[128], ww[128];
  __shared__ float normsq[128];
  __shared__ float dotv[256];
  __shared__ float scal[12];
  __shared__ float red2[4];
  __shared__ float bias_big[512];                  // [be | ba | bk0 | bk1]
  __shared__ float bh_l[256];
  __shared__ float bias_sm[12];

  // ===== C-matmul weights resident in regs: 64 f16x2 (fits 128-reg cap w/o spill)
  f16x2 wcreg[64];
  {
    const float* basep = (js < 4) ? (Wx + (js * 32) * 256) : (Wrd + ((js - 4) * 32) * 256);
    #pragma unroll
    for (int c = 0; c < 4; ++c) {
      const float* bp = basep + c * 64 + cg;
      #pragma unroll
      for (int jj = 0; jj < 16; ++jj) {
        wcreg[c * 16 + jj] = pack2(bp[(2 * jj) * 256], bp[(2 * jj + 1) * 256]);
      }
    }
  }

  // ===== state / bias / small-weight init =====
  for (int i = t; i < 128 * 128; i += NT) mem[i] = mem0[i];
  if (t < 128) { wr[t] = wr0[b * 128 + t]; ww[t] = ww0[b * 128 + t]; }
  if (t < 256) { h_l[t] = h0[b * 256 + t]; bh_l[t] = bh[t]; }
  bias_big[t] = (t < 128) ? be[t] : (t < 256) ? ba[t - 128] : bk[t - 256];
  for (int i = t; i < 3072; i += NT) {
    const int d = i >> 8, j = i & 255;
    const int head = d / 6, kind = d % 6;
    float v;
    if (kind == 0)      v = Wb[head * 256 + j];
    else if (kind == 1) v = Wg[head * 256 + j];
    else if (kind == 2) v = Wgam[head * 256 + j];
    else                v = Ws[head * 768 + j * 3 + (kind - 3)];
    wsm_l[i] = v;
  }
  if (t < 12) {
    const int head = t / 6, kind = t % 6;
    bias_sm[t] = (kind == 0) ? bb[head] : (kind == 1) ? bg[head]
               : (kind == 2) ? bgam[head] : bs[head * 3 + (kind - 3)];
  }
  __syncthreads();

  // ---- big4 matmul partials: h16 from LDS, weights STREAMED from L2 (wsb)
  auto phase_big4 = [&]() {
    f16x2 hh[16];
    #pragma unroll
    for (int jj = 0; jj < 16; ++jj) {
      const float2 h2 = *reinterpret_cast<const float2*>(&h_l[js * 32 + 2 * jj]);
      hh[jj] = pack2(h2.x, h2.y);
    }
    float acc[8];
    #pragma unroll
    for (int c = 0; c < 8; ++c) acc[c] = 0.f;
    #pragma unroll
    for (int c = 0; c < 8; ++c) {
      // uint4 index: ((c*8+js)*4 + jj4)*64 + cg  -> 64 lanes x 16B contiguous
      const uint4* p = wsb + (c * 8 + js) * 256 + cg;
      uint4 w0 = p[0];
      uint4 w1 = p[64];
      uint4 w2 = p[128];
      uint4 w3 = p[192];
      acc[c] = dot2(hh[0],  __builtin_bit_cast(f16x2, w0.x), acc[c]);
      acc[c] = dot2(hh[1],  __builtin_bit_cast(f16x2, w0.y), acc[c]);
      acc[c] = dot2(hh[2],  __builtin_bit_cast(f16x2, w0.z), acc[c]);
      acc[c] = dot2(hh[3],  __builtin_bit_cast(f16x2, w0.w), acc[c]);
      acc[c] = dot2(hh[4],  __builtin_bit_cast(f16x2, w1.x), acc[c]);
      acc[c] = dot2(hh[5],  __builtin_bit_cast(f16x2, w1.y), acc[c]);
      acc[c] = dot2(hh[6],  __builtin_bit_cast(f16x2, w1.z), acc[c]);
      acc[c] = dot2(hh[7],  __builtin_bit_cast(f16x2, w1.w), acc[c]);
      acc[c] = dot2(hh[8],  __builtin_bit_cast(f16x2, w2.x), acc[c]);
      acc[c] = dot2(hh[9],  __builtin_bit_cast(f16x2, w2.y), acc[c]);
      acc[c] = dot2(hh[10], __builtin_bit_cast(f16x2, w2.z), acc[c]);
      acc[c] = dot2(hh[11], __builtin_bit_cast(f16x2, w2.w), acc[c]);
      acc[c] = dot2(hh[12], __builtin_bit_cast(f16x2, w3.x), acc[c]);
      acc[c] = dot2(hh[13], __builtin_bit_cast(f16x2, w3.y), acc[c]);
      acc[c] = dot2(hh[14], __builtin_bit_cast(f16x2, w3.z), acc[c]);
      acc[c] = dot2(hh[15], __builtin_bit_cast(f16x2, w3.w), acc[c]);
    }
    #pragma unroll
    for (int c = 0; c < 8; ++c) part[js * 512 + c * 64 + cg] = acc[c];
  };

  // ---- reduce big4 -> er/ad/kbuf + k^2 (DPP) + 12 small dots (DPP)
  auto phase_reduce = [&]() {
    {
      float v = bias_big[t];
      #pragma unroll
      for (int s = 0; s < 8; ++s) v += part[s * 512 + t];
      if (t < 128)      er[t] = fsigmoid(v);
      else if (t < 256) ad[t - 128] = ftanh(v);
      else {
        float kv = ftanh(v);
        kbuf[t - 256] = kv;
        float ks = kv * kv;
        ks = halfsum(ks); ks = dppadd<0x143>(ks);
        if (lane == 63) red2[wave - 4] = ks;
      }
    }
    if (t < 384) {
      const int d = t >> 5, l5 = t & 31;
      float s = 0.f;
      #pragma unroll
      for (int q = 0; q < 8; ++q) s += h_l[l5 + 32 * q] * wsm_l[d * 256 + l5 + 32 * q];
      s = halfsum(s);
      if ((lane & 31) == 31) scal[d] = s + bias_sm[d];
    }
  };

  // prologue: er/ad/k/scal for step 0 from h0
  phase_big4();
  __syncthreads();
  phase_reduce();
  __syncthreads();

  for (int step = 0; step < Tt; ++step) {
    // ---- P1: x_t -> xf; mem erase/add update; r partials
    if (t < 128) xf[t] = x[((size_t)b * Tt + step) * 128 + t];
    {
      const float4 e4 = *reinterpret_cast<const float4*>(&er[c4 * 4]);
      const float4 a4 = *reinterpret_cast<const float4*>(&ad[c4 * 4]);
      float rx = 0.f, ry = 0.f, rz = 0.f, rw = 0.f;
      #pragma unroll
      for (int k = 0; k < 8; ++k) {
        const int n = rs + 16 * k;
        const float wwn = ww[n], wrn = wr[n];
        float4 v = *reinterpret_cast<const float4*>(&mem[n * 128 + c4 * 4]);
        v.x = v.x * (1.f - wwn * e4.x) + wwn * a4.x;
        v.y = v.y * (1.f - wwn * e4.y) + wwn * a4.y;
        v.z = v.z * (1.f - wwn * e4.z) + wwn * a4.z;
        v.w = v.w * (1.f - wwn * e4.w) + wwn * a4.w;
        *reinterpret_cast<float4*>(&mem[n * 128 + c4 * 4]) = v;
        rx += wrn * v.x; ry += wrn * v.y; rz += wrn * v.z; rw += wrn * v.w;
      }
      *reinterpret_cast<float4*>(&part[rs * 128 + c4 * 4]) = make_float4(rx, ry, rz, rw);
    }
    __syncthreads();  // b1

    // ---- P2: reduce r partials
    if (t < 128) {
      float r = 0.f;
      #pragma unroll
      for (int s = 0; s < 16; ++s) r += part[s * 128 + t];
      rf[t] = r;
    }
    __syncthreads();  // b2

    // ---- P3: C-matmul partials from [xf|rf] (reg-resident weights)
    {
      const float* src = (js < 4) ? (xf + js * 32) : (rf + (js - 4) * 32);
      float acc[4];
      #pragma unroll
      for (int c = 0; c < 4; ++c) acc[c] = 0.f;
      #pragma unroll
      for (int jj = 0; jj < 16; ++jj) {
        const float2 s2 = *reinterpret_cast<const float2*>(&src[2 * jj]);
        const f16x2 xx = pack2(s2.x, s2.y);
        #pragma unroll
        for (int c = 0; c < 4; ++c) acc[c] = dot2(xx, wcreg[c * 16 + jj], acc[c]);
      }
      #pragma unroll
      for (int c = 0; c < 4; ++c) part[js * 256 + c * 64 + cg] = acc[c];
    }
    __syncthreads();  // b3

    // ---- P4: h = tanh(.); write out
    if (t < 256) {
      float v = bh_l[t];
      #pragma unroll
      for (int s = 0; s < 8; ++s) v += part[s * 256 + t];
      v = ftanh(v);
      h_l[t] = v;
      out[((size_t)b * Tt + step) * 256 + t] = v;
    }
    __syncthreads();  // b4

    // ---- P5/P6: big4 + reduce from new h
    phase_big4();
    __syncthreads();  // b5
    phase_reduce();
    __syncthreads();  // b6

    // ---- P7: content dots + row normsq fused (DPP half-reduction)
    {
      const int head = t >> 8;           // waves 0-3: head0, 4-7: head1
      const int u = t & 255;
      const int cc = u & 31, ns = u >> 5; // half-wave owns 16 rows
      const float4 k4 = *reinterpret_cast<const float4*>(&kbuf[head * 128 + cc * 4]);
      #pragma unroll
      for (int ch = 0; ch < 2; ++ch) {
        float dsum[8], qsum[8];
        #pragma unroll
        for (int ii = 0; ii < 8; ++ii) {
          const int n = ns * 16 + ch * 8 + ii;
          const float4 m4 = *reinterpret_cast<const float4*>(&mem[n * 128 + cc * 4]);
          dsum[ii] = k4.x * m4.x + k4.y * m4.y + k4.z * m4.z + k4.w * m4.w;
          qsum[ii] = m4.x * m4.x + m4.y * m4.y + m4.z * m4.z + m4.w * m4.w;
        }
        #pragma unroll
        for (int ii = 0; ii < 8; ++ii) dsum[ii] = halfsum(dsum[ii]);
        if (head == 0) {
          #pragma unroll
          for (int ii = 0; ii < 8; ++ii) qsum[ii] = halfsum(qsum[ii]);
        }
        if ((lane & 31) == 31) {
          #pragma unroll
          for (int ii = 0; ii < 8; ++ii) dotv[head * 128 + ns * 16 + ch * 8 + ii] = dsum[ii];
          if (head == 0) {
            #pragma unroll
            for (int ii = 0; ii < 8; ++ii) normsq[ns * 16 + ch * 8 + ii] = qsum[ii];
          }
        }
      }
    }
    __syncthreads();  // b7

    // ---- P8: addressing tail, wave0=head0, wave1=head1 (DPP all-reduces)
    if (wave < 2) {
      const int head = wave;
      const int h6 = head * 6;
      const float beta  = fsoftplus(scal[h6]);
      const float g     = fsigmoid(scal[h6 + 1]);
      const float gamma = 1.f + fsoftplus(scal[h6 + 2]);
      float e0 = scal[h6 + 3], e1 = scal[h6 + 4], e2 = scal[h6 + 5];
      const float mx3 = fmaxf(e0, fmaxf(e1, e2));
      float x0 = expf(e0 - mx3), x1 = expf(e1 - mx3), x2 = expf(e2 - mx3);
      const float si = 1.f / (x0 + x1 + x2);
      const float s0 = x0 * si, s1 = x1 * si, s2 = x2 * si;
      const float knorm = sqrtf(red2[2 * head] + red2[2 * head + 1]);
      float* wprev = head ? ww : wr;
      const int n0 = 2 * lane, n1 = 2 * lane + 1;
      float l0 = beta * dotv[head * 128 + n0] / (knorm * sqrtf(normsq[n0]) + EPSF);
      float l1 = beta * dotv[head * 128 + n1] / (knorm * sqrtf(normsq[n1]) + EPSF);
      const float mx = allmax(fmaxf(l0, l1));
      float q0 = expf(l0 - mx), q1 = expf(l1 - mx);
      const float inv = 1.f / allsum(q0 + q1);
      const float wg0 = g * q0 * inv + (1.f - g) * wprev[n0];
      const float wg1 = g * q1 * inv + (1.f - g) * wprev[n1];
      const float wgl = __shfl(wg1, (lane + 63) & 63);
      const float wgr = __shfl(wg0, (lane + 1) & 63);
      const float sh0 = s0 * wgl + s1 * wg0 + s2 * wg1;
      const float sh1 = s0 * wg0 + s1 * wg1 + s2 * wgr;
      const float wp0 = exp2f(gamma * log2f(sh0));
      const float wp1 = exp2f(gamma * log2f(sh1));
      const float itot = 1.f / (allsum(wp0 + wp1) + EPSF);
      wprev[n0] = wp0 * itot;
      wprev[n1] = wp1 * itot;
    }
    __syncthreads();  // b8
  }
}

extern "C" void kernel_launch(void* const* d_in, const int* in_sizes, int n_in,
                              void* d_out, int out_size, void* d_ws, size_t ws_size,
                              hipStream_t stream) {
  const float* x    = (const float*)d_in[0];
  const float* mem0 = (const float*)d_in[1];
  const float* wr0  = (const float*)d_in[2];
  const float* ww0  = (const float*)d_in[3];
  const float* h0   = (const float*)d_in[4];
  const float* Wx   = (const float*)d_in[5];
  const float* Wrd  = (const float*)d_in[6];
  const float* bh   = (const float*)d_in[7];
  const float* Wk   = (const float*)d_in[8];
  const float* bk   = (const float*)d_in[9];
  const float* Wb   = (const float*)d_in[10];
  const float* bb   = (const float*)d_in[11];
  const float* Wg   = (const float*)d_in[12];
  const float* bg   = (const float*)d_in[13];
  const float* Ws   = (const float*)d_in[14];
  const float* bs   = (const float*)d_in[15];
  const float* Wgam = (const float*)d_in[16];
  const float* bgam = (const float*)d_in[17];
  const float* We   = (const float*)d_in[18];
  const float* be   = (const float*)d_in[19];
  const float* Wa   = (const float*)d_in[20];
  const float* ba   = (const float*)d_in[21];
  float* out = (float*)d_out;
  unsigned int* wsb = (unsigned int*)d_ws;   // 65536 uints = 256 KB

  hipLaunchKernelGGL(ntm_prep, dim3(128), dim3(512), 0, stream, We, Wa, Wk, wsb);
  hipLaunchKernelGGL(ntm_kernel, dim3(128), dim3(NT), 0, stream,
                     x, mem0, wr0, ww0, h0, Wx, Wrd, bh, bk, Wb, bb,
                     Wg, bg, Ws, bs, Wgam, bgam, be, ba,
                     (const uint4*)wsb, out);
}